// Round 10
// baseline (229.404 us; speedup 1.0000x reference)
//
#include <hip/hip_runtime.h>
#include <math.h>

#define BATCH 4096
#define NC    8192
#define DIM   512
#define KEXP  5
#define NCAND 10

using bf16x8 = __attribute__((ext_vector_type(8))) short;
using f32x4  = __attribute__((ext_vector_type(4))) float;
typedef unsigned long long u64;

// module-scope device buffers (no hipMalloc; deterministic, rewritten every call)
__device__ unsigned short g_zbf[BATCH * DIM];   // 4 MB bf16(z)
__device__ unsigned short g_cbf[NC * DIM];      // 8 MB bf16(centers)
__device__ float g_z2[BATCH];
__device__ float g_c2[NC];

__device__ __forceinline__ unsigned short rtne_bf16(float f) {
  unsigned u = __float_as_uint(f);
  u += 0x7FFFu + ((u >> 16) & 1u);
  return (unsigned short)(u >> 16);
}

__device__ __forceinline__ void gload16(const void* g, void* l) {
  __builtin_amdgcn_global_load_lds(
      (const __attribute__((address_space(1))) void*)g,
      (__attribute__((address_space(3))) void*)l, 16, 0, 0);
}

// ---------------------------------------------------------------------------
// Kernel 0: f32 -> bf16 (RTN) conversion FUSED with f64 row-norms.
// ---------------------------------------------------------------------------
__global__ __launch_bounds__(256) void convert_kernel(const float* __restrict__ z,
                                                      const float* __restrict__ c) {
  const size_t i = ((size_t)blockIdx.x * 256 + threadIdx.x) * 8;
  const size_t zn = (size_t)BATCH * DIM;
  const float* src;
  unsigned short* dst;
  float* ndst;
  size_t off;
  if (i < zn) { src = z; dst = g_zbf; ndst = g_z2; off = i; }
  else        { src = c; dst = g_cbf; ndst = g_c2; off = i - zn; }
  float4 a = *(const float4*)(src + off);
  float4 b = *(const float4*)(src + off + 4);
  uint4 o;
  o.x = (unsigned)rtne_bf16(a.x) | ((unsigned)rtne_bf16(a.y) << 16);
  o.y = (unsigned)rtne_bf16(a.z) | ((unsigned)rtne_bf16(a.w) << 16);
  o.z = (unsigned)rtne_bf16(b.x) | ((unsigned)rtne_bf16(b.y) << 16);
  o.w = (unsigned)rtne_bf16(b.z) | ((unsigned)rtne_bf16(b.w) << 16);
  *(uint4*)(dst + off) = o;

  double s = (double)a.x * a.x + (double)a.y * a.y + (double)a.z * a.z + (double)a.w * a.w +
             (double)b.x * b.x + (double)b.y * b.y + (double)b.z * b.z + (double)b.w * b.w;
#pragma unroll
  for (int sh = 32; sh > 0; sh >>= 1) s += __shfl_xor(s, sh);
  if ((threadIdx.x & 63) == 0) ndst[off / DIM] = (float)s;
}

// ---------------------------------------------------------------------------
// Kernel 2: attractions GEMM, B-panel-resident, BARRIER-FREE main loop.
// Block = 128 att-cols x 1024 att-rows; grid = 256 = 1 block/CU (one round).
// B-panel (128 x 512 bf16 = 128 KB) staged to LDS ONCE (coalesced row-per-
// instr gload16, XOR-granule swizzle g ^= row&7) -> single __syncthreads.
// Main loop: 8 waves x 2 chunks of 64 rows; per K-step: 4 A-frag loads
// global->reg (A L2-resident; per-XCD B-set = 1 MB via col-block swizzle),
// 8 B ds_read_b128 (conflict-free), 32 MFMA. No barriers -> loads hide
// under the MFMA stream instead of being drained every step.
// Swapped operands mfma(fb,fa): acc reg-dim along att cols -> dwordx4.
// ---------------------------------------------------------------------------
__global__ __launch_bounds__(512, 2) void attr_bf16(const float* __restrict__ mus,
                                                    float* __restrict__ att) {
  __shared__ __align__(16) unsigned short Bp[128 * DIM];   // 128 KB

  const int tid  = threadIdx.x;
  const int lane = tid & 63;
  const int wv   = tid >> 6;        // 0..7
  const int l15  = lane & 15;
  const int q    = lane >> 4;       // 0..3

  // XCD swizzle: blocks with same (flat&7) share an XCD -> give them a
  // contiguous col-block range (B L2-locality). cb in 0..63, m in 0..3.
  const int flat = blockIdx.x;                  // 256 blocks
  const int swz  = (flat & 7) * 32 + (flat >> 3);
  const int cb   = swz >> 2;                    // col-block (128 cols)
  const int m    = swz & 3;                     // m-chunk (1024 rows)
  const int col0 = cb * 128;
  const int mrow0 = m * 1024;

  // ---- stage B-panel once: wave wv stages rows wv*16 .. +16 ----
  {
    const unsigned short* Bg = g_cbf + (size_t)col0 * DIM;
#pragma unroll
    for (int t = 0; t < 16; ++t) {
      const int r = wv * 16 + t;
      // LDS row r linear; source granule pre-swizzled: lane ^ (r&7)
      gload16(Bg + (size_t)r * DIM + (size_t)((lane ^ (r & 7)) & 63) * 8,
              &Bp[r * DIM]);
    }
  }
  __syncthreads();   // the ONLY barrier

  const float* zz2 = g_z2;

  // ---- 2 chunks of 64 rows per wave ----
#pragma unroll
  for (int chunk = 0; chunk < 2; ++chunk) {
    const int rbase = mrow0 + wv * 128 + chunk * 64;
    const unsigned short* Ag = g_zbf + (size_t)rbase * DIM;

    f32x4 acc[4][8];
#pragma unroll
    for (int i = 0; i < 4; ++i)
#pragma unroll
      for (int j = 0; j < 8; ++j) acc[i][j] = (f32x4)(0.0f);

#pragma unroll 2
    for (int kst = 0; kst < 16; ++kst) {
      const int G = kst * 4 + q;            // global k-granule for this lane
      bf16x8 fa[4], fb[8];
#pragma unroll
      for (int i = 0; i < 4; ++i)
        fa[i] = *(const bf16x8*)(Ag + (size_t)(i * 16 + l15) * DIM + G * 8);
#pragma unroll
      for (int j = 0; j < 8; ++j) {
        const int r = j * 16 + l15;
        fb[j] = *(const bf16x8*)(&Bp[r * DIM + ((G ^ (r & 7)) * 8)]);
      }
#pragma unroll
      for (int i = 0; i < 4; ++i)
#pragma unroll
        for (int j = 0; j < 8; ++j)
          acc[i][j] = __builtin_amdgcn_mfma_f32_16x16x32_bf16(fb[j], fa[i], acc[i][j], 0, 0, 0);
    }

    // ---- epilogue for this chunk (validated mapping + dwordx4) ----
#pragma unroll
    for (int i = 0; i < 4; ++i) {
      const int ar = rbase + i * 16 + l15;
      const float zz = zz2[ar];
      float* dst = att + (size_t)ar * NC;
#pragma unroll
      for (int j = 0; j < 8; ++j) {
        const int gc0 = col0 + j * 16 + q * 4;
        const float4 cc = *(const float4*)&g_c2[gc0];
        const float4 mu = *(const float4*)&mus[gc0];
        const float ccv[4] = {cc.x, cc.y, cc.z, cc.w};
        const float muv[4] = {mu.x, mu.y, mu.z, mu.w};
        float o[4];
#pragma unroll
        for (int r = 0; r < 4; ++r) {
          float ttv = __fadd_rn(zz, ccv[r]);
          float sq  = __fsub_rn(ttv, __fmul_rn(2.0f, acc[i][j][r]));
          float d   = sqrtf(fmaxf(sq, 0.0f));
          float den = __fadd_rn(__fmul_rn(d, d), 1e-6f);
          o[r] = __fdiv_rn(muv[r], den);
        }
        *(float4*)(dst + gc0) = *(const float4*)o;
      }
    }
  }
}

// ---------------------------------------------------------------------------
// Kernel 3: wave-per-row top-NCAND via packed-key pop-lists (unchanged).
// ---------------------------------------------------------------------------
__global__ __launch_bounds__(256, 4) void topk_kernel(const float* __restrict__ att,
                                                      const float* __restrict__ z,
                                                      const float* __restrict__ centers,
                                                      const float* __restrict__ mus,
                                                      float* __restrict__ out) {
  __shared__ int selLds[4][16];
  const int lane = threadIdx.x & 63;
  const int wv   = threadIdx.x >> 6;
  const int row  = blockIdx.x * 4 + wv;
  const float4* arow4 = (const float4*)(att + (size_t)row * NC);

  u64 k[8][4];
#pragma unroll
  for (int c = 0; c < 8; ++c) {
#pragma unroll
    for (int j = 0; j < 4; ++j) k[c][j] = 0ull;
#pragma unroll
    for (int qq = 0; qq < 4; ++qq) {
      float4 v4 = arow4[c * 256 + qq * 64 + lane];
      const unsigned ib = (unsigned)(c * 1024 + qq * 256 + lane * 4);
      const float vv[4] = {v4.x, v4.y, v4.z, v4.w};
#pragma unroll
      for (int e = 0; e < 4; ++e) {
        u64 nk = ((u64)__float_as_uint(vv[e]) << 32) | (u64)(0xFFFFFFFFu - (ib + e));
        bool g0 = nk > k[c][0], g1 = nk > k[c][1], g2 = nk > k[c][2], g3 = nk > k[c][3];
        u64 t0 = k[c][0], t1 = k[c][1], t2 = k[c][2];
        k[c][0] = g0 ? nk : k[c][0];
        k[c][1] = g0 ? t0 : (g1 ? nk : k[c][1]);
        k[c][2] = g1 ? t1 : (g2 ? nk : k[c][2]);
        k[c][3] = g2 ? t2 : (g3 ? nk : k[c][3]);
      }
    }
  }

  for (int it = 0; it < NCAND; ++it) {
    u64 b = k[0][0];
#pragma unroll
    for (int c = 1; c < 8; ++c) b = (k[c][0] > b) ? k[c][0] : b;
#pragma unroll
    for (int off = 32; off > 0; off >>= 1) {
      u64 o = __shfl_xor(b, off);
      b = (o > b) ? o : b;
    }
    if (lane == 0) selLds[wv][it] = (int)(0xFFFFFFFFu - (unsigned)(b & 0xFFFFFFFFu));
#pragma unroll
    for (int c = 0; c < 8; ++c) {
      bool hit = (k[c][0] == b);
      k[c][0] = hit ? k[c][1] : k[c][0];
      k[c][1] = hit ? k[c][2] : k[c][1];
      k[c][2] = hit ? k[c][3] : k[c][2];
      k[c][3] = hit ? 0ull    : k[c][3];
    }
  }

  const float* zrow = z + (size_t)row * DIM;
  const int d0 = lane * 8;
  const float4 za = *(const float4*)(zrow + d0);
  const float4 zb = *(const float4*)(zrow + d0 + 4);
  const float myz2 = g_z2[row];

  double p[NCAND];
  int cidx[NCAND];
#pragma unroll
  for (int c = 0; c < NCAND; ++c) {
    cidx[c] = selLds[wv][c];
    const float* cp = centers + (size_t)cidx[c] * DIM + d0;
    float4 ca = *(const float4*)(cp);
    float4 cb = *(const float4*)(cp + 4);
    p[c] = (double)za.x * ca.x + (double)za.y * ca.y +
           (double)za.z * ca.z + (double)za.w * ca.w +
           (double)zb.x * cb.x + (double)zb.y * cb.y +
           (double)zb.z * cb.z + (double)zb.w * cb.w;
  }
#pragma unroll
  for (int off = 32; off > 0; off >>= 1) {
#pragma unroll
    for (int c = 0; c < NCAND; ++c) p[c] += __shfl_xor(p[c], off);
  }

  float exv[NCAND];
#pragma unroll
  for (int c = 0; c < NCAND; ++c) {
    const int ci = cidx[c];
    float dotf = (float)p[c];
    float t   = __fadd_rn(myz2, g_c2[ci]);
    float sq  = __fsub_rn(t, __fmul_rn(2.0f, dotf));
    float d   = sqrtf(fmaxf(sq, 0.0f));
    float den = __fadd_rn(__fmul_rn(d, d), 1e-6f);
    exv[c] = __fdiv_rn(mus[ci], den);
  }

  unsigned used = 0;
  float tv[KEXP]; int tix[KEXP];
#pragma unroll
  for (int s = 0; s < KEXP; ++s) {
    float bv = -INFINITY; int bi = 0x7FFFFFFF; int bc = 0;
#pragma unroll
    for (int c = 0; c < NCAND; ++c) {
      bool ok = (used & (1u << c)) == 0;
      if (ok && (exv[c] > bv || (exv[c] == bv && cidx[c] < bi))) {
        bv = exv[c]; bi = cidx[c]; bc = c;
      }
    }
    used |= (1u << bc);
    tv[s] = bv; tix[s] = bi;
  }

  float mm = tv[0];
  float w[KEXP];
  float s = 0.0f;
#pragma unroll
  for (int kk = 0; kk < KEXP; ++kk) { w[kk] = expf(tv[kk] - mm); s += w[kk]; }
#pragma unroll
  for (int kk = 0; kk < KEXP; ++kk) w[kk] /= s;

  float comb[8] = {0, 0, 0, 0, 0, 0, 0, 0};
#pragma unroll
  for (int kk = 0; kk < KEXP; ++kk) {
    const float* cp = centers + (size_t)tix[kk] * DIM + d0;
    float4 a = *(const float4*)(cp);
    float4 bq = *(const float4*)(cp + 4);
    comb[0] += w[kk] * a.x;  comb[1] += w[kk] * a.y;
    comb[2] += w[kk] * a.z;  comb[3] += w[kk] * a.w;
    comb[4] += w[kk] * bq.x; comb[5] += w[kk] * bq.y;
    comb[6] += w[kk] * bq.z; comb[7] += w[kk] * bq.w;
  }
  const float zv[8] = {za.x, za.y, za.z, za.w, zb.x, zb.y, zb.z, zb.w};
  float o[8];
#pragma unroll
  for (int e = 0; e < 8; ++e)
    o[e] = __fadd_rn(__fmul_rn(0.7f, zv[e]), __fmul_rn(0.3f, comb[e]));
  *(float4*)(out + (size_t)row * DIM + d0)     = *(float4*)&o[0];
  *(float4*)(out + (size_t)row * DIM + d0 + 4) = *(float4*)&o[4];
}

// ---------------------------------------------------------------------------
extern "C" void kernel_launch(void* const* d_in, const int* in_sizes, int n_in,
                              void* d_out, int out_size, void* d_ws, size_t ws_size,
                              hipStream_t stream) {
  const float* z       = (const float*)d_in[0];
  const float* centers = (const float*)d_in[1];
  const float* mus     = (const float*)d_in[2];
  float* out      = (float*)d_out;
  float* expanded = out;
  float* att      = out + (size_t)BATCH * DIM;

  convert_kernel<<<(BATCH + NC) * DIM / (256 * 8), 256, 0, stream>>>(z, centers);
  attr_bf16<<<256, 512, 0, stream>>>(mus, att);
  topk_kernel<<<BATCH / 4, 256, 0, stream>>>(att, z, centers, mus, expanded);
}